// Round 8
// baseline (366.188 us; speedup 1.0000x reference)
//
#include <hip/hip_runtime.h>
#include <hip/hip_bf16.h>

typedef __hip_bfloat16 bf16;
typedef __attribute__((ext_vector_type(8))) short short8;
typedef __attribute__((ext_vector_type(16))) float f32x16;

#define NS 256      // N_SEQ
#define NR 256      // N_RES
#define CM 256      // C_M
#define CZ 128      // C_Z
#define NH 8        // heads
#define CH 32       // head dim
#define LN_EPS 1e-5f
#define LOG2E 1.4426950408889634f
// (1/sqrt(32)) * log2(e): folded into w_q at pack time
#define SCALE2 (0.17677669529663687f * 1.4426950408889634f)

__device__ __forceinline__ unsigned pk_bf16(float lo, float hi) {
  unsigned r;
  asm volatile("v_cvt_pk_bf16_f32 %0, %1, %2" : "=v"(r) : "v"(lo), "v"(hi));
  return r;
}

__device__ __forceinline__ short8 load8(const bf16* p) {
  return __builtin_bit_cast(short8, *(const uint4*)p);
}

// ---------------------------------------------------------------------------
// Kernel 0: pack 5 weight matrices (each [256][256] f32) into bf16 B-frag
// layout: wp[mat][kc][hi][n][j] = w[kc*16 + hi*8 + j][n]
// w_q is pre-scaled by (1/sqrt(32))*log2(e).
// ---------------------------------------------------------------------------
__global__ __launch_bounds__(256) void pack_w_kernel(
    const float* __restrict__ wq, const float* __restrict__ wk,
    const float* __restrict__ wv, const float* __restrict__ wg,
    const float* __restrict__ wo, bf16* __restrict__ dst) {
  int mat = blockIdx.y;
  const float* src = mat == 0 ? wq : mat == 1 ? wk : mat == 2 ? wv
                   : mat == 3 ? wg : wo;
  float sc = (mat == 0) ? SCALE2 : 1.0f;
  int t = blockIdx.x * 256 + threadIdx.x;  // 0..8191
  int n = t & 255;
  int hi = (t >> 8) & 1;
  int kc = t >> 9;
  int kbase = kc * 16 + hi * 8;
  bf16 tmp[8];
  #pragma unroll
  for (int j = 0; j < 8; ++j)
    tmp[j] = __float2bfloat16(src[(size_t)(kbase + j) * 256 + n] * sc);
  *(uint4*)(dst + (size_t)mat * 65536 +
            ((size_t)(kc * 2 + hi) * 256 + n) * 8) = *(const uint4*)tmp;
}

// ---------------------------------------------------------------------------
// Kernel 1: LayerNorm over m, one wave per row, float4 loads, bf16x4 stores
// ---------------------------------------------------------------------------
__global__ __launch_bounds__(256) void ln_m_kernel(
    const float* __restrict__ m, const float* __restrict__ w,
    const float* __restrict__ b, bf16* __restrict__ mn) {
  int row = blockIdx.x * 4 + (threadIdx.x >> 6);
  int lane = threadIdx.x & 63;

  float4 x = ((const float4*)(m + (size_t)row * CM))[lane];
  float sum = x.x + x.y + x.z + x.w;
  #pragma unroll
  for (int off = 32; off; off >>= 1) sum += __shfl_xor(sum, off);
  float mu = sum * (1.0f / CM);

  float dx = x.x - mu, dy = x.y - mu, dz = x.z - mu, dw = x.w - mu;
  float ss = dx * dx + dy * dy + dz * dz + dw * dw;
  #pragma unroll
  for (int off = 32; off; off >>= 1) ss += __shfl_xor(ss, off);
  float rs = rsqrtf(ss * (1.0f / CM) + LN_EPS);

  float4 wv = ((const float4*)w)[lane];
  float4 bv = ((const float4*)b)[lane];
  unsigned p0 = pk_bf16(dx * rs * wv.x + bv.x, dy * rs * wv.y + bv.y);
  unsigned p1 = pk_bf16(dz * rs * wv.z + bv.z, dw * rs * wv.w + bv.w);
  uint2 u;
  u.x = p0;
  u.y = p1;
  *(uint2*)(mn + (size_t)row * CM + lane * 4) = u;
}

// ---------------------------------------------------------------------------
// Kernel 2: bias in wave-coalesced attn fragment layout:
//   biasP[(((h*8 + qt)*128) + i) * 64 + lane] = bias[h][q][k] * log2(e)
// where q = qt*32 + (lane&31), i = t*16 + r, k = t*32 + crow(r, lane>>5),
//       crow(r,hi) = (r&3) + 8*(r>>2) + 4*hi.
// ---------------------------------------------------------------------------
__global__ __launch_bounds__(128) void bias_kernel(
    const float* __restrict__ z, const float* __restrict__ w,
    const float* __restrict__ b, const float* __restrict__ wz,
    float* __restrict__ biasP) {
  int row = blockIdx.x;   // i*NR + j  (i = q, j = k)
  int t = threadIdx.x;    // 0..127
  __shared__ float red[2];
  __shared__ float zn[CZ];
  __shared__ float part[16][9];

  float x = z[(size_t)row * CZ + t];

  float v = x;
  #pragma unroll
  for (int off = 32; off; off >>= 1) v += __shfl_xor(v, off);
  if ((t & 63) == 0) red[t >> 6] = v;
  __syncthreads();
  float mu = (red[0] + red[1]) * (1.0f / CZ);
  float d = x - mu;
  __syncthreads();

  v = d * d;
  #pragma unroll
  for (int off = 32; off; off >>= 1) v += __shfl_xor(v, off);
  if ((t & 63) == 0) red[t >> 6] = v;
  __syncthreads();
  float var = (red[0] + red[1]) * (1.0f / CZ);

  zn[t] = d * rsqrtf(var + LN_EPS) * w[t] + b[t];
  __syncthreads();

  int h = t & 7, grp = t >> 3;
  float acc = 0.0f;
  #pragma unroll
  for (int cc = 0; cc < 8; ++cc) {
    int c = grp * 8 + cc;
    acc += zn[c] * wz[c * NH + h];
  }
  part[grp][h] = acc;
  __syncthreads();

  if (t < NH) {
    float s = 0.0f;
    #pragma unroll
    for (int g = 0; g < 16; ++g) s += part[g][t];
    int i = row >> 8, j = row & 255;         // q = i, k = j
    int qt = i >> 5, lo = i & 31;
    int tt = j >> 5, rem = j & 31;
    int hi2 = (rem >> 2) & 1;
    int r = ((rem >> 3) << 2) | (rem & 3);
    biasP[(((size_t)t * 8 + qt) * 128 + tt * 16 + r) * 64 + hi2 * 32 + lo] =
        s * LOG2E;
  }
}

// ---------------------------------------------------------------------------
// Kernel 3: fused q/k/v/g projections via MFMA, accumulator-resident form.
// Block = 4 waves on the SAME matrix, 4 consecutive 32-row m-tiles -> B-frag
// stream is L1-shared 4x (barrier every 4 kc keeps the waves aligned).
// ---------------------------------------------------------------------------
__global__ __launch_bounds__(256, 2) void qkvg_mfma_kernel(
    const bf16* __restrict__ mn, const bf16* __restrict__ wp,
    const float* __restrict__ bg,
    bf16* __restrict__ qo, bf16* __restrict__ ko,
    bf16* __restrict__ vo, bf16* __restrict__ go) {
  int wave = threadIdx.x >> 6;
  int lane = threadIdx.x & 63;
  int lo = lane & 31, hi = lane >> 5;
  int mat = blockIdx.x & 3;
  int mg = blockIdx.x >> 2;
  size_t m0 = ((size_t)mg * 4 + wave) * 32;

  const bf16* arow = mn + (m0 + lo) * 256 + hi * 8;
  const bf16* wbase = wp + (size_t)mat * 65536 + ((size_t)hi * 256 + lo) * 8;

  f32x16 acc[8] = {};
  #pragma unroll 4
  for (int kc = 0; kc < 16; ++kc) {
    short8 a = load8(arow + kc * 16);
    const bf16* wkc = wbase + (size_t)kc * 4096;
    #pragma unroll
    for (int nt = 0; nt < 8; ++nt) {
      short8 b = load8(wkc + nt * 256);
      acc[nt] = __builtin_amdgcn_mfma_f32_32x32x16_bf16(a, b, acc[nt], 0, 0, 0);
    }
    if ((kc & 3) == 3) __syncthreads();  // keep 4 waves' B-streams L1-aligned
  }

  bf16* outp = mat == 0 ? qo : mat == 1 ? ko : mat == 2 ? vo : go;
  if (mat == 3) {
    #pragma unroll
    for (int nt = 0; nt < 8; ++nt) {
      float bgv = bg[nt * 32 + lo];
      #pragma unroll
      for (int r = 0; r < 16; ++r) {
        int crow = (r & 3) + ((r >> 2) << 3) + (hi << 2);
        float sv = 1.0f / (1.0f + __expf(-(acc[nt][r] + bgv)));
        outp[(m0 + crow) * 256 + nt * 32 + lo] = __float2bfloat16(sv);
      }
    }
  } else {
    #pragma unroll
    for (int nt = 0; nt < 8; ++nt) {
      #pragma unroll
      for (int r = 0; r < 16; ++r) {
        int crow = (r & 3) + ((r >> 2) << 3) + (hi << 2);
        outp[(m0 + crow) * 256 + nt * 32 + lo] = __float2bfloat16(acc[nt][r]);
      }
    }
  }
}

// ---------------------------------------------------------------------------
// Kernel 3b: vT[s][h][c][k] = vo[s][k][h*32+c]. One block per (s,h), LDS tile.
// ---------------------------------------------------------------------------
__global__ __launch_bounds__(256) void transpose_v_kernel(
    const bf16* __restrict__ vo, bf16* __restrict__ vT) {
  int s = blockIdx.x >> 3, h = blockIdx.x & 7;
  int t = threadIdx.x;
  __shared__ bf16 tile[256][40];  // stride 80 B (16B-aligned), conflict-light

  #pragma unroll
  for (int p = 0; p < 4; ++p) {
    int k = p * 64 + (t >> 2);
    int c0 = (t & 3) * 8;
    uint4 u = *(const uint4*)(vo + ((size_t)(s * 256 + k)) * 256 + h * 32 + c0);
    *(uint4*)&tile[k][c0] = u;
  }
  __syncthreads();

  int c = t >> 3, k0 = (t & 7) * 32;
  bf16 buf[32];
  #pragma unroll
  for (int j = 0; j < 32; ++j) buf[j] = tile[k0 + j][c];
  bf16* dst = vT + (((size_t)(s * 8 + h) * 32 + c) * 256 + k0);
  #pragma unroll
  for (int q = 0; q < 4; ++q)
    *(uint4*)(dst + q * 8) = *(const uint4*)(buf + q * 8);
}

// ---------------------------------------------------------------------------
// Kernel 4: online MFMA attention, one wave per (s, h, 32-q tile).
// Per 32-k tile t: QK MFMA -> bias+exp2 (NO max subtraction: log2-domain
// logits are bounded ~ +-18, f32/bf16-safe) -> pack P via cvt_pk +
// v_permlane32_swap -> PV MFMA. Only one 16-value fragment live at a time
// -> ~90 VGPR -> 4 waves/SIMD. XCD-swizzled block id for K/V L2 locality.
// ---------------------------------------------------------------------------
__global__ __launch_bounds__(256, 4) void attn_mfma_kernel(
    const bf16* __restrict__ qb, const bf16* __restrict__ kb,
    const bf16* __restrict__ vT, const bf16* __restrict__ gb,
    const float* __restrict__ biasP, bf16* __restrict__ gob) {
  // XCD swizzle: chunk the 4096-block grid so consecutive work-blocks
  // (which share K/V slices and s-rows) land on one XCD.
  int wb = (blockIdx.x & 7) * 512 + (blockIdx.x >> 3);
  int wid = wb * 4 + (threadIdx.x >> 6);
  int lane = threadIdx.x & 63;
  int lo = lane & 31;
  int hi = lane >> 5;
  int s = wid >> 6;
  int h = (wid >> 3) & 7;
  int qt = wid & 7;
  int q0 = qt * 32;

  const size_t base = (size_t)s * NR * 256 + h * CH;

  // this lane's 128 bias values, wave-coalesced: bp[i*64], i = t*16+r
  const float* bp = biasP + (((size_t)h * 8 + qt) * 128) * 64 + lane;

  short8 qf[2];
  #pragma unroll
  for (int cc = 0; cc < 2; ++cc)
    qf[cc] = load8(qb + base + (size_t)(q0 + lo) * 256 + cc * 16 + hi * 8);

  const bf16* vt = vT + ((size_t)(s * NH + h) * CH + lo) * 256;

  f32x16 o = {};
  float l0 = 0.0f, l1 = 0.0f, l2 = 0.0f, l3 = 0.0f;

  #pragma unroll
  for (int t = 0; t < 8; ++t) {
    short8 kf0 = load8(kb + base + (size_t)(t * 32 + lo) * 256 + hi * 8);
    short8 kf1 = load8(kb + base + (size_t)(t * 32 + lo) * 256 + 16 + hi * 8);
    f32x16 a = {};
    a = __builtin_amdgcn_mfma_f32_32x32x16_bf16(kf0, qf[0], a, 0, 0, 0);
    a = __builtin_amdgcn_mfma_f32_32x32x16_bf16(kf1, qf[1], a, 0, 0, 0);

    // bias + exp2, 4 parallel sum accumulators (no max: bounded logits)
    #pragma unroll
    for (int r = 0; r < 16; r += 4) {
      float e0 = exp2f(a[r + 0] + bp[(t * 16 + r + 0) * 64]);
      float e1 = exp2f(a[r + 1] + bp[(t * 16 + r + 1) * 64]);
      float e2 = exp2f(a[r + 2] + bp[(t * 16 + r + 2) * 64]);
      float e3 = exp2f(a[r + 3] + bp[(t * 16 + r + 3) * 64]);
      a[r + 0] = e0;
      a[r + 1] = e1;
      a[r + 2] = e2;
      a[r + 3] = e3;
      l0 += e0;
      l1 += e1;
      l2 += e2;
      l3 += e3;
    }

    // pack P fragments and do PV for the two 16-k halves of this tile
    #pragma unroll
    for (int half = 0; half < 2; ++half) {
      int rb = half << 3;
      unsigned uL0 = pk_bf16(a[rb + 0], a[rb + 1]);
      unsigned uL1 = pk_bf16(a[rb + 2], a[rb + 3]);
      unsigned uH0 = pk_bf16(a[rb + 4], a[rb + 5]);
      unsigned uH1 = pk_bf16(a[rb + 6], a[rb + 7]);
      // uL0' = {uL0.lo, uH0.lo} (= pu.x), uH0' = {uL0.hi, uH0.hi} (= pu.z)
      asm volatile("v_permlane32_swap_b32 %0, %1" : "+v"(uL0), "+v"(uH0));
      asm volatile("v_permlane32_swap_b32 %0, %1" : "+v"(uL1), "+v"(uH1));
      uint4 pu;
      pu.x = uL0;
      pu.y = uL1;
      pu.z = uH0;
      pu.w = uH1;
      short8 pf = __builtin_bit_cast(short8, pu);
      short8 vf = load8(vt + (t * 2 + half) * 16 + hi * 8);
      o = __builtin_amdgcn_mfma_f32_32x32x16_bf16(pf, vf, o, 0, 0, 0);
    }
  }

  float l = (l0 + l1) + (l2 + l3);
  l += __shfl_xor(l, 32);
  float linv = 1.0f / l;

  #pragma unroll
  for (int r = 0; r < 16; ++r) {
    int crow = (r & 3) + ((r >> 2) << 3) + (hi << 2);
    float li = __shfl(linv, crow);
    size_t idx = base + (size_t)(q0 + crow) * 256 + lo;
    float gg = __bfloat162float(gb[idx]);
    gob[idx] = __float2bfloat16(gg * o[r] * li);
  }
}

// ---------------------------------------------------------------------------
// Kernel 5: out = (g*o) @ w_o + b_o via MFMA, accumulator-resident form.
// ---------------------------------------------------------------------------
__global__ __launch_bounds__(256, 2) void out_mfma_kernel(
    const bf16* __restrict__ gob, const bf16* __restrict__ wop,
    const float* __restrict__ bo, float* __restrict__ out) {
  int wid = blockIdx.x * 4 + (threadIdx.x >> 6);
  int lane = threadIdx.x & 63;
  int lo = lane & 31, hi = lane >> 5;
  size_t m0 = (size_t)wid * 32;

  const bf16* arow = gob + (m0 + lo) * 256 + hi * 8;
  const bf16* wbase = wop + ((size_t)hi * 256 + lo) * 8;

  f32x16 acc[8] = {};
  #pragma unroll 2
  for (int kc = 0; kc < 16; ++kc) {
    short8 a = load8(arow + kc * 16);
    const bf16* wkc = wbase + (size_t)kc * 4096;
    #pragma unroll
    for (int nt = 0; nt < 8; ++nt) {
      short8 b = load8(wkc + nt * 256);
      acc[nt] = __builtin_amdgcn_mfma_f32_32x32x16_bf16(a, b, acc[nt], 0, 0, 0);
    }
  }

  #pragma unroll
  for (int nt = 0; nt < 8; ++nt) {
    float bv = bo[nt * 32 + lo];
    #pragma unroll
    for (int r = 0; r < 16; ++r) {
      int crow = (r & 3) + ((r >> 2) << 3) + (hi << 2);
      out[(m0 + crow) * 256 + nt * 32 + lo] = acc[nt][r] + bv;
    }
  }
}

// ---------------------------------------------------------------------------
extern "C" void kernel_launch(void* const* d_in, const int* in_sizes, int n_in,
                              void* d_out, int out_size, void* d_ws, size_t ws_size,
                              hipStream_t stream) {
  const float* m      = (const float*)d_in[0];
  const float* z      = (const float*)d_in[1];
  const float* ln_m_w = (const float*)d_in[2];
  const float* ln_m_b = (const float*)d_in[3];
  const float* ln_z_w = (const float*)d_in[4];
  const float* ln_z_b = (const float*)d_in[5];
  const float* w_z    = (const float*)d_in[6];
  const float* w_q    = (const float*)d_in[7];
  const float* w_k    = (const float*)d_in[8];
  const float* w_v    = (const float*)d_in[9];
  const float* w_g    = (const float*)d_in[10];
  const float* b_g    = (const float*)d_in[11];
  const float* w_o    = (const float*)d_in[12];
  const float* b_o    = (const float*)d_in[13];
  float* out = (float*)d_out;

  const size_t SZ = (size_t)NS * NR * 256;

  bf16* mn   = (bf16*)d_ws;
  bf16* qb   = mn + SZ;
  bf16* kb   = qb + SZ;
  bf16* vo   = kb + SZ;
  bf16* gb   = vo + SZ;
  bf16* gob  = gb + SZ;
  float* biasP = (float*)(gob + SZ);            // 2 MB
  bf16* wp   = (bf16*)(biasP + NH * NR * NR);   // 5*65536 bf16 = 640 KB
  bf16* wop  = wp + 4 * 65536;
  bf16* vT   = mn;  // mn is dead after qkvg; reuse its slot for vT

  pack_w_kernel<<<dim3(32, 5), 256, 0, stream>>>(w_q, w_k, w_v, w_g, w_o, wp);
  ln_m_kernel<<<(NS * NR) / 4, 256, 0, stream>>>(m, ln_m_w, ln_m_b, mn);
  bias_kernel<<<NR * NR, 128, 0, stream>>>(z, ln_z_w, ln_z_b, w_z, biasP);
  qkvg_mfma_kernel<<<(NS * NR) / 32, 256, 0, stream>>>(mn, wp, b_g,
                                                       qb, kb, vo, gb);
  transpose_v_kernel<<<NS * NH, 256, 0, stream>>>(vo, vT);
  attn_mfma_kernel<<<(NS * NH * 8) / 4, 256, 0, stream>>>(qb, kb, vT, gb,
                                                          biasP, gob);
  out_mfma_kernel<<<(NS * NR) / 32 / 4, 256, 0, stream>>>(gob, wop, b_o, out);
}

// Round 9
// 311.616 us; speedup vs baseline: 1.1751x; 1.1751x over previous
//
#include <hip/hip_runtime.h>
#include <hip/hip_bf16.h>

typedef __hip_bfloat16 bf16;
typedef __attribute__((ext_vector_type(8))) short short8;
typedef __attribute__((ext_vector_type(16))) float f32x16;

#define NS 256      // N_SEQ
#define NR 256      // N_RES
#define CM 256      // C_M
#define CZ 128      // C_Z
#define NH 8        // heads
#define CH 32       // head dim
#define LN_EPS 1e-5f
#define LOG2E 1.4426950408889634f
// (1/sqrt(32)) * log2(e): folded into w_q at pack time
#define SCALE2 (0.17677669529663687f * 1.4426950408889634f)

__device__ __forceinline__ unsigned pk_bf16(float lo, float hi) {
  unsigned r;
  asm volatile("v_cvt_pk_bf16_f32 %0, %1, %2" : "=v"(r) : "v"(lo), "v"(hi));
  return r;
}

__device__ __forceinline__ short8 load8(const bf16* p) {
  return __builtin_bit_cast(short8, *(const uint4*)p);
}

// ---------------------------------------------------------------------------
// Kernel 0: pack 5 weight matrices (each [256][256] f32) into bf16 B-frag
// layout: wp[mat][kc][hi][n][j] = w[kc*16 + hi*8 + j][n]
// w_q is pre-scaled by (1/sqrt(32))*log2(e).
// ---------------------------------------------------------------------------
__global__ __launch_bounds__(256) void pack_w_kernel(
    const float* __restrict__ wq, const float* __restrict__ wk,
    const float* __restrict__ wv, const float* __restrict__ wg,
    const float* __restrict__ wo, bf16* __restrict__ dst) {
  int mat = blockIdx.y;
  const float* src = mat == 0 ? wq : mat == 1 ? wk : mat == 2 ? wv
                   : mat == 3 ? wg : wo;
  float sc = (mat == 0) ? SCALE2 : 1.0f;
  int t = blockIdx.x * 256 + threadIdx.x;  // 0..8191
  int n = t & 255;
  int hi = (t >> 8) & 1;
  int kc = t >> 9;
  int kbase = kc * 16 + hi * 8;
  bf16 tmp[8];
  #pragma unroll
  for (int j = 0; j < 8; ++j)
    tmp[j] = __float2bfloat16(src[(size_t)(kbase + j) * 256 + n] * sc);
  *(uint4*)(dst + (size_t)mat * 65536 +
            ((size_t)(kc * 2 + hi) * 256 + n) * 8) = *(const uint4*)tmp;
}

// ---------------------------------------------------------------------------
// Kernel 1: LayerNorm over m, one wave per row, float4 loads, bf16x4 stores
// ---------------------------------------------------------------------------
__global__ __launch_bounds__(256) void ln_m_kernel(
    const float* __restrict__ m, const float* __restrict__ w,
    const float* __restrict__ b, bf16* __restrict__ mn) {
  int row = blockIdx.x * 4 + (threadIdx.x >> 6);
  int lane = threadIdx.x & 63;

  float4 x = ((const float4*)(m + (size_t)row * CM))[lane];
  float sum = x.x + x.y + x.z + x.w;
  #pragma unroll
  for (int off = 32; off; off >>= 1) sum += __shfl_xor(sum, off);
  float mu = sum * (1.0f / CM);

  float dx = x.x - mu, dy = x.y - mu, dz = x.z - mu, dw = x.w - mu;
  float ss = dx * dx + dy * dy + dz * dz + dw * dw;
  #pragma unroll
  for (int off = 32; off; off >>= 1) ss += __shfl_xor(ss, off);
  float rs = rsqrtf(ss * (1.0f / CM) + LN_EPS);

  float4 wv = ((const float4*)w)[lane];
  float4 bv = ((const float4*)b)[lane];
  unsigned p0 = pk_bf16(dx * rs * wv.x + bv.x, dy * rs * wv.y + bv.y);
  unsigned p1 = pk_bf16(dz * rs * wv.z + bv.z, dw * rs * wv.w + bv.w);
  uint2 u;
  u.x = p0;
  u.y = p1;
  *(uint2*)(mn + (size_t)row * CM + lane * 4) = u;
}

// ---------------------------------------------------------------------------
// Kernel 2: bias in wave-coalesced attn fragment layout:
//   biasP[(((h*8 + qt)*128) + i) * 64 + lane] = bias[h][q][k] * log2(e)
// where q = qt*32 + (lane&31), i = t*16 + r, k = t*32 + crow(r, lane>>5),
//       crow(r,hi) = (r&3) + 8*(r>>2) + 4*hi.
// ---------------------------------------------------------------------------
__global__ __launch_bounds__(128) void bias_kernel(
    const float* __restrict__ z, const float* __restrict__ w,
    const float* __restrict__ b, const float* __restrict__ wz,
    float* __restrict__ biasP) {
  int row = blockIdx.x;   // i*NR + j  (i = q, j = k)
  int t = threadIdx.x;    // 0..127
  __shared__ float red[2];
  __shared__ float zn[CZ];
  __shared__ float part[16][9];

  float x = z[(size_t)row * CZ + t];

  float v = x;
  #pragma unroll
  for (int off = 32; off; off >>= 1) v += __shfl_xor(v, off);
  if ((t & 63) == 0) red[t >> 6] = v;
  __syncthreads();
  float mu = (red[0] + red[1]) * (1.0f / CZ);
  float d = x - mu;
  __syncthreads();

  v = d * d;
  #pragma unroll
  for (int off = 32; off; off >>= 1) v += __shfl_xor(v, off);
  if ((t & 63) == 0) red[t >> 6] = v;
  __syncthreads();
  float var = (red[0] + red[1]) * (1.0f / CZ);

  zn[t] = d * rsqrtf(var + LN_EPS) * w[t] + b[t];
  __syncthreads();

  int h = t & 7, grp = t >> 3;
  float acc = 0.0f;
  #pragma unroll
  for (int cc = 0; cc < 8; ++cc) {
    int c = grp * 8 + cc;
    acc += zn[c] * wz[c * NH + h];
  }
  part[grp][h] = acc;
  __syncthreads();

  if (t < NH) {
    float s = 0.0f;
    #pragma unroll
    for (int g = 0; g < 16; ++g) s += part[g][t];
    int i = row >> 8, j = row & 255;         // q = i, k = j
    int qt = i >> 5, lo = i & 31;
    int tt = j >> 5, rem = j & 31;
    int hi2 = (rem >> 2) & 1;
    int r = ((rem >> 3) << 2) | (rem & 3);
    biasP[(((size_t)t * 8 + qt) * 128 + tt * 16 + r) * 64 + hi2 * 32 + lo] =
        s * LOG2E;
  }
}

// ---------------------------------------------------------------------------
// Kernel 3: fused q/k/v/g projections via MFMA, accumulator-resident form.
// Block = 4 waves sharing one 32-row A-tile (L1 reuse); wave = one matrix.
// (reverted to the round-6 independent-wave form; the barrier-synced variant
// regressed ~13 us)
// ---------------------------------------------------------------------------
__global__ __launch_bounds__(256, 2) void qkvg_mfma_kernel(
    const bf16* __restrict__ mn, const bf16* __restrict__ wp,
    const float* __restrict__ bg,
    bf16* __restrict__ qo, bf16* __restrict__ ko,
    bf16* __restrict__ vo, bf16* __restrict__ go) {
  int mat = threadIdx.x >> 6;  // wave id = matrix (q,k,v,g)
  int lane = threadIdx.x & 63;
  int lo = lane & 31, hi = lane >> 5;
  size_t m0 = (size_t)blockIdx.x * 32;

  const bf16* arow = mn + (m0 + lo) * 256 + hi * 8;
  const bf16* wbase = wp + (size_t)mat * 65536 + ((size_t)hi * 256 + lo) * 8;

  f32x16 acc[8] = {};
  #pragma unroll 2
  for (int kc = 0; kc < 16; ++kc) {
    short8 a = load8(arow + kc * 16);
    const bf16* wkc = wbase + (size_t)kc * 4096;
    #pragma unroll
    for (int nt = 0; nt < 8; ++nt) {
      short8 b = load8(wkc + nt * 256);
      acc[nt] = __builtin_amdgcn_mfma_f32_32x32x16_bf16(a, b, acc[nt], 0, 0, 0);
    }
  }

  bf16* outp = mat == 0 ? qo : mat == 1 ? ko : mat == 2 ? vo : go;
  if (mat == 3) {
    #pragma unroll
    for (int nt = 0; nt < 8; ++nt) {
      float bgv = bg[nt * 32 + lo];
      #pragma unroll
      for (int r = 0; r < 16; ++r) {
        int crow = (r & 3) + ((r >> 2) << 3) + (hi << 2);
        float sv = 1.0f / (1.0f + __expf(-(acc[nt][r] + bgv)));
        outp[(m0 + crow) * 256 + nt * 32 + lo] = __float2bfloat16(sv);
      }
    }
  } else {
    #pragma unroll
    for (int nt = 0; nt < 8; ++nt) {
      #pragma unroll
      for (int r = 0; r < 16; ++r) {
        int crow = (r & 3) + ((r >> 2) << 3) + (hi << 2);
        outp[(m0 + crow) * 256 + nt * 32 + lo] = __float2bfloat16(acc[nt][r]);
      }
    }
  }
}

// ---------------------------------------------------------------------------
// Kernel 3b: vT[s][h][c][k] = vo[s][k][h*32+c]. One block per (s,h), LDS tile.
// ---------------------------------------------------------------------------
__global__ __launch_bounds__(256) void transpose_v_kernel(
    const bf16* __restrict__ vo, bf16* __restrict__ vT) {
  int s = blockIdx.x >> 3, h = blockIdx.x & 7;
  int t = threadIdx.x;
  __shared__ bf16 tile[256][40];  // stride 80 B (16B-aligned), conflict-light

  #pragma unroll
  for (int p = 0; p < 4; ++p) {
    int k = p * 64 + (t >> 2);
    int c0 = (t & 3) * 8;
    uint4 u = *(const uint4*)(vo + ((size_t)(s * 256 + k)) * 256 + h * 32 + c0);
    *(uint4*)&tile[k][c0] = u;
  }
  __syncthreads();

  int c = t >> 3, k0 = (t & 7) * 32;
  bf16 buf[32];
  #pragma unroll
  for (int j = 0; j < 32; ++j) buf[j] = tile[k0 + j][c];
  bf16* dst = vT + (((size_t)(s * 8 + h) * 32 + c) * 256 + k0);
  #pragma unroll
  for (int q = 0; q < 4; ++q)
    *(uint4*)(dst + q * 8) = *(const uint4*)(buf + q * 8);
}

// ---------------------------------------------------------------------------
// Kernel 4: MFMA attention, one wave per (s, h, 32-q tile). Round-6 phase
// structure (QK MFMA burst -> softmax -> pack+PV) with two grafts:
//  (a) XCD-swizzled block id (FETCH 167->90 MB, measured round 7),
//  (b) no-max softmax: log2-domain logits are bounded (~+-12), so
//      P = exp2(logit + bias) directly; max tree + 128 subs deleted.
// ---------------------------------------------------------------------------
__global__ __launch_bounds__(256, 2) void attn_mfma_kernel(
    const bf16* __restrict__ qb, const bf16* __restrict__ kb,
    const bf16* __restrict__ vT, const bf16* __restrict__ gb,
    const float* __restrict__ biasP, bf16* __restrict__ gob) {
  // XCD swizzle: consecutive work ids (sharing s and (s,h) K/V slices)
  // land on one XCD's L2.
  int wb = (blockIdx.x & 7) * 512 + (blockIdx.x >> 3);
  int wid = wb * 4 + (threadIdx.x >> 6);
  int lane = threadIdx.x & 63;
  int lo = lane & 31;
  int hi = lane >> 5;
  int s = wid >> 6;
  int h = (wid >> 3) & 7;
  int qt = wid & 7;
  int q0 = qt * 32;

  const size_t base = (size_t)s * NR * 256 + h * CH;

  // this lane's 128 bias values, wave-coalesced: bp[i*64], i = t*16+r
  const float* bp = biasP + (((size_t)h * 8 + qt) * 128) * 64 + lane;

  short8 qf[2];
  #pragma unroll
  for (int cc = 0; cc < 2; ++cc)
    qf[cc] = load8(qb + base + (size_t)(q0 + lo) * 256 + cc * 16 + hi * 8);

  f32x16 acc[8];
  __builtin_amdgcn_s_setprio(1);
  #pragma unroll
  for (int t = 0; t < 8; ++t) {
    short8 kf0 = load8(kb + base + (size_t)(t * 32 + lo) * 256 + hi * 8);
    short8 kf1 = load8(kb + base + (size_t)(t * 32 + lo) * 256 + 16 + hi * 8);
    f32x16 z = {};
    acc[t] = __builtin_amdgcn_mfma_f32_32x32x16_bf16(kf0, qf[0], z, 0, 0, 0);
    acc[t] = __builtin_amdgcn_mfma_f32_32x32x16_bf16(kf1, qf[1], acc[t], 0, 0, 0);
  }
  __builtin_amdgcn_s_setprio(0);

  // P = exp2(logit + bias); 4 parallel sum accumulators (no max needed:
  // log2-domain logits bounded ~ +-12, f32-safe; normalization by l below)
  float l0 = 0.0f, l1 = 0.0f, l2 = 0.0f, l3 = 0.0f;
  #pragma unroll
  for (int t = 0; t < 8; ++t) {
    #pragma unroll
    for (int r = 0; r < 16; r += 4) {
      float e0 = exp2f(acc[t][r + 0] + bp[(t * 16 + r + 0) * 64]);
      float e1 = exp2f(acc[t][r + 1] + bp[(t * 16 + r + 1) * 64]);
      float e2 = exp2f(acc[t][r + 2] + bp[(t * 16 + r + 2) * 64]);
      float e3 = exp2f(acc[t][r + 3] + bp[(t * 16 + r + 3) * 64]);
      acc[t][r + 0] = e0;
      acc[t][r + 1] = e1;
      acc[t][r + 2] = e2;
      acc[t][r + 3] = e3;
      l0 += e0;
      l1 += e1;
      l2 += e2;
      l3 += e3;
    }
  }
  float l = (l0 + l1) + (l2 + l3);
  l += __shfl_xor(l, 32);

  f32x16 o = {};
  const bf16* vt = vT + ((size_t)(s * NH + h) * CH + lo) * 256;
  #pragma unroll
  for (int kc = 0; kc < 16; ++kc) {
    int t = kc >> 1;
    int rb = (kc & 1) << 3;
    unsigned uL0 = pk_bf16(acc[t][rb + 0], acc[t][rb + 1]);
    unsigned uL1 = pk_bf16(acc[t][rb + 2], acc[t][rb + 3]);
    unsigned uH0 = pk_bf16(acc[t][rb + 4], acc[t][rb + 5]);
    unsigned uH1 = pk_bf16(acc[t][rb + 6], acc[t][rb + 7]);
    unsigned sL0 = __shfl_xor(uL0, 32), sL1 = __shfl_xor(uL1, 32);
    unsigned sH0 = __shfl_xor(uH0, 32), sH1 = __shfl_xor(uH1, 32);
    uint4 pu;
    pu.x = hi ? sH0 : uL0;
    pu.y = hi ? sH1 : uL1;
    pu.z = hi ? uH0 : sL0;
    pu.w = hi ? uH1 : sL1;
    short8 pf = __builtin_bit_cast(short8, pu);
    short8 vf = load8(vt + kc * 16 + hi * 8);
    o = __builtin_amdgcn_mfma_f32_32x32x16_bf16(pf, vf, o, 0, 0, 0);
  }

  float linv = 1.0f / l;
  #pragma unroll
  for (int r = 0; r < 16; ++r) {
    int crow = (r & 3) + ((r >> 2) << 3) + (hi << 2);
    float li = __shfl(linv, crow);
    size_t idx = base + (size_t)(q0 + crow) * 256 + lo;
    float gg = __bfloat162float(gb[idx]);
    gob[idx] = __float2bfloat16(gg * o[r] * li);
  }
}

// ---------------------------------------------------------------------------
// Kernel 5: out = (g*o) @ w_o + b_o via MFMA, accumulator-resident form.
// ---------------------------------------------------------------------------
__global__ __launch_bounds__(256, 2) void out_mfma_kernel(
    const bf16* __restrict__ gob, const bf16* __restrict__ wop,
    const float* __restrict__ bo, float* __restrict__ out) {
  int wid = blockIdx.x * 4 + (threadIdx.x >> 6);
  int lane = threadIdx.x & 63;
  int lo = lane & 31, hi = lane >> 5;
  size_t m0 = (size_t)wid * 32;

  const bf16* arow = gob + (m0 + lo) * 256 + hi * 8;
  const bf16* wbase = wop + ((size_t)hi * 256 + lo) * 8;

  f32x16 acc[8] = {};
  #pragma unroll 2
  for (int kc = 0; kc < 16; ++kc) {
    short8 a = load8(arow + kc * 16);
    const bf16* wkc = wbase + (size_t)kc * 4096;
    #pragma unroll
    for (int nt = 0; nt < 8; ++nt) {
      short8 b = load8(wkc + nt * 256);
      acc[nt] = __builtin_amdgcn_mfma_f32_32x32x16_bf16(a, b, acc[nt], 0, 0, 0);
    }
  }

  #pragma unroll
  for (int nt = 0; nt < 8; ++nt) {
    float bv = bo[nt * 32 + lo];
    #pragma unroll
    for (int r = 0; r < 16; ++r) {
      int crow = (r & 3) + ((r >> 2) << 3) + (hi << 2);
      out[(m0 + crow) * 256 + nt * 32 + lo] = acc[nt][r] + bv;
    }
  }
}

// ---------------------------------------------------------------------------
extern "C" void kernel_launch(void* const* d_in, const int* in_sizes, int n_in,
                              void* d_out, int out_size, void* d_ws, size_t ws_size,
                              hipStream_t stream) {
  const float* m      = (const float*)d_in[0];
  const float* z      = (const float*)d_in[1];
  const float* ln_m_w = (const float*)d_in[2];
  const float* ln_m_b = (const float*)d_in[3];
  const float* ln_z_w = (const float*)d_in[4];
  const float* ln_z_b = (const float*)d_in[5];
  const float* w_z    = (const float*)d_in[6];
  const float* w_q    = (const float*)d_in[7];
  const float* w_k    = (const float*)d_in[8];
  const float* w_v    = (const float*)d_in[9];
  const float* w_g    = (const float*)d_in[10];
  const float* b_g    = (const float*)d_in[11];
  const float* w_o    = (const float*)d_in[12];
  const float* b_o    = (const float*)d_in[13];
  float* out = (float*)d_out;

  const size_t SZ = (size_t)NS * NR * 256;

  bf16* mn   = (bf16*)d_ws;
  bf16* qb   = mn + SZ;
  bf16* kb   = qb + SZ;
  bf16* vo   = kb + SZ;
  bf16* gb   = vo + SZ;
  bf16* gob  = gb + SZ;
  float* biasP = (float*)(gob + SZ);            // 2 MB
  bf16* wp   = (bf16*)(biasP + NH * NR * NR);   // 5*65536 bf16 = 640 KB
  bf16* wop  = wp + 4 * 65536;
  bf16* vT   = mn;  // mn is dead after qkvg; reuse its slot for vT

  pack_w_kernel<<<dim3(32, 5), 256, 0, stream>>>(w_q, w_k, w_v, w_g, w_o, wp);
  ln_m_kernel<<<(NS * NR) / 4, 256, 0, stream>>>(m, ln_m_w, ln_m_b, mn);
  bias_kernel<<<NR * NR, 128, 0, stream>>>(z, ln_z_w, ln_z_b, w_z, biasP);
  qkvg_mfma_kernel<<<(NS * NR) / 32, 256, 0, stream>>>(mn, wp, b_g,
                                                       qb, kb, vo, gb);
  transpose_v_kernel<<<NS * NH, 256, 0, stream>>>(vo, vT);
  attn_mfma_kernel<<<(NS * NH * 8) / 4, 256, 0, stream>>>(qb, kb, vT, gb,
                                                          biasP, gob);
  out_mfma_kernel<<<(NS * NR) / 32 / 4, 256, 0, stream>>>(gob, wop, b_o, out);
}

// Round 10
// 299.251 us; speedup vs baseline: 1.2237x; 1.0413x over previous
//
#include <hip/hip_runtime.h>
#include <hip/hip_bf16.h>

typedef __hip_bfloat16 bf16;
typedef __attribute__((ext_vector_type(8))) short short8;
typedef __attribute__((ext_vector_type(16))) float f32x16;

#define NS 256      // N_SEQ
#define NR 256      // N_RES
#define CM 256      // C_M
#define CZ 128      // C_Z
#define NH 8        // heads
#define CH 32       // head dim
#define LN_EPS 1e-5f
#define LOG2E 1.4426950408889634f
// (1/sqrt(32)) * log2(e): folded into w_q at pack time
#define SCALE2 (0.17677669529663687f * 1.4426950408889634f)

__device__ __forceinline__ unsigned pk_bf16(float lo, float hi) {
  unsigned r;
  asm volatile("v_cvt_pk_bf16_f32 %0, %1, %2" : "=v"(r) : "v"(lo), "v"(hi));
  return r;
}

__device__ __forceinline__ short8 load8(const bf16* p) {
  return __builtin_bit_cast(short8, *(const uint4*)p);
}

// ---------------------------------------------------------------------------
// Kernel 0: pack 5 weight matrices (each [256][256] f32) into bf16 B-frag
// layout: wp[mat][kc][hi][n][j] = w[kc*16 + hi*8 + j][n]
// w_q is pre-scaled by (1/sqrt(32))*log2(e).
// ---------------------------------------------------------------------------
__global__ __launch_bounds__(256) void pack_w_kernel(
    const float* __restrict__ wq, const float* __restrict__ wk,
    const float* __restrict__ wv, const float* __restrict__ wg,
    const float* __restrict__ wo, bf16* __restrict__ dst) {
  int mat = blockIdx.y;
  const float* src = mat == 0 ? wq : mat == 1 ? wk : mat == 2 ? wv
                   : mat == 3 ? wg : wo;
  float sc = (mat == 0) ? SCALE2 : 1.0f;
  int t = blockIdx.x * 256 + threadIdx.x;  // 0..8191
  int n = t & 255;
  int hi = (t >> 8) & 1;
  int kc = t >> 9;
  int kbase = kc * 16 + hi * 8;
  bf16 tmp[8];
  #pragma unroll
  for (int j = 0; j < 8; ++j)
    tmp[j] = __float2bfloat16(src[(size_t)(kbase + j) * 256 + n] * sc);
  *(uint4*)(dst + (size_t)mat * 65536 +
            ((size_t)(kc * 2 + hi) * 256 + n) * 8) = *(const uint4*)tmp;
}

// ---------------------------------------------------------------------------
// Kernel 1: LayerNorm over m, one wave per row, float4 loads, bf16x4 stores
// ---------------------------------------------------------------------------
__global__ __launch_bounds__(256) void ln_m_kernel(
    const float* __restrict__ m, const float* __restrict__ w,
    const float* __restrict__ b, bf16* __restrict__ mn) {
  int row = blockIdx.x * 4 + (threadIdx.x >> 6);
  int lane = threadIdx.x & 63;

  float4 x = ((const float4*)(m + (size_t)row * CM))[lane];
  float sum = x.x + x.y + x.z + x.w;
  #pragma unroll
  for (int off = 32; off; off >>= 1) sum += __shfl_xor(sum, off);
  float mu = sum * (1.0f / CM);

  float dx = x.x - mu, dy = x.y - mu, dz = x.z - mu, dw = x.w - mu;
  float ss = dx * dx + dy * dy + dz * dz + dw * dw;
  #pragma unroll
  for (int off = 32; off; off >>= 1) ss += __shfl_xor(ss, off);
  float rs = rsqrtf(ss * (1.0f / CM) + LN_EPS);

  float4 wv = ((const float4*)w)[lane];
  float4 bv = ((const float4*)b)[lane];
  unsigned p0 = pk_bf16(dx * rs * wv.x + bv.x, dy * rs * wv.y + bv.y);
  unsigned p1 = pk_bf16(dz * rs * wv.z + bv.z, dw * rs * wv.w + bv.w);
  uint2 u;
  u.x = p0;
  u.y = p1;
  *(uint2*)(mn + (size_t)row * CM + lane * 4) = u;
}

// ---------------------------------------------------------------------------
// Kernel 2: bias in float4-vectorized, wave-coalesced attn fragment layout:
//   biasP[(((h*8+qt)*32 + i4)*64 + lane)*4 + lj] = bias[h][q][k] * log2(e)
// where q = qt*32 + (lane&31), fragment index i = i4*4 + lj = t*16 + r,
// k = t*32 + crow(r, lane>>5), crow(r,hi) = (r&3) + 8*(r>>2) + 4*hi.
// Attn lane reads 32 float4s (1 KB per wave-instr, fully coalesced).
// ---------------------------------------------------------------------------
__global__ __launch_bounds__(128) void bias_kernel(
    const float* __restrict__ z, const float* __restrict__ w,
    const float* __restrict__ b, const float* __restrict__ wz,
    float* __restrict__ biasP) {
  int row = blockIdx.x;   // i*NR + j  (i = q, j = k)
  int t = threadIdx.x;    // 0..127
  __shared__ float red[2];
  __shared__ float zn[CZ];
  __shared__ float part[16][9];

  float x = z[(size_t)row * CZ + t];

  float v = x;
  #pragma unroll
  for (int off = 32; off; off >>= 1) v += __shfl_xor(v, off);
  if ((t & 63) == 0) red[t >> 6] = v;
  __syncthreads();
  float mu = (red[0] + red[1]) * (1.0f / CZ);
  float d = x - mu;
  __syncthreads();

  v = d * d;
  #pragma unroll
  for (int off = 32; off; off >>= 1) v += __shfl_xor(v, off);
  if ((t & 63) == 0) red[t >> 6] = v;
  __syncthreads();
  float var = (red[0] + red[1]) * (1.0f / CZ);

  zn[t] = d * rsqrtf(var + LN_EPS) * w[t] + b[t];
  __syncthreads();

  int h = t & 7, grp = t >> 3;
  float acc = 0.0f;
  #pragma unroll
  for (int cc = 0; cc < 8; ++cc) {
    int c = grp * 8 + cc;
    acc += zn[c] * wz[c * NH + h];
  }
  part[grp][h] = acc;
  __syncthreads();

  if (t < NH) {
    float s = 0.0f;
    #pragma unroll
    for (int g = 0; g < 16; ++g) s += part[g][t];
    int i = row >> 8, j = row & 255;         // q = i, k = j
    int qt = i >> 5, lo = i & 31;
    int tt = j >> 5, rem = j & 31;
    int hi2 = (rem >> 2) & 1;
    int r = ((rem >> 3) << 2) | (rem & 3);
    int ifrag = tt * 16 + r;
    int lane = hi2 * 32 + lo;
    biasP[((((size_t)t * 8 + qt) * 32 + (ifrag >> 2)) * 64 + lane) * 4 +
          (ifrag & 3)] = s * LOG2E;
  }
}

// ---------------------------------------------------------------------------
// Kernel 3: fused q/k/v/g projections via MFMA, accumulator-resident form.
// Block = 4 waves sharing one 32-row A-tile (L1 reuse); wave = one matrix.
// ---------------------------------------------------------------------------
__global__ __launch_bounds__(256, 2) void qkvg_mfma_kernel(
    const bf16* __restrict__ mn, const bf16* __restrict__ wp,
    const float* __restrict__ bg,
    bf16* __restrict__ qo, bf16* __restrict__ ko,
    bf16* __restrict__ vo, bf16* __restrict__ go) {
  int mat = threadIdx.x >> 6;  // wave id = matrix (q,k,v,g)
  int lane = threadIdx.x & 63;
  int lo = lane & 31, hi = lane >> 5;
  size_t m0 = (size_t)blockIdx.x * 32;

  const bf16* arow = mn + (m0 + lo) * 256 + hi * 8;
  const bf16* wbase = wp + (size_t)mat * 65536 + ((size_t)hi * 256 + lo) * 8;

  f32x16 acc[8] = {};
  #pragma unroll 2
  for (int kc = 0; kc < 16; ++kc) {
    short8 a = load8(arow + kc * 16);
    const bf16* wkc = wbase + (size_t)kc * 4096;
    #pragma unroll
    for (int nt = 0; nt < 8; ++nt) {
      short8 b = load8(wkc + nt * 256);
      acc[nt] = __builtin_amdgcn_mfma_f32_32x32x16_bf16(a, b, acc[nt], 0, 0, 0);
    }
  }

  bf16* outp = mat == 0 ? qo : mat == 1 ? ko : mat == 2 ? vo : go;
  if (mat == 3) {
    #pragma unroll
    for (int nt = 0; nt < 8; ++nt) {
      float bgv = bg[nt * 32 + lo];
      #pragma unroll
      for (int r = 0; r < 16; ++r) {
        int crow = (r & 3) + ((r >> 2) << 3) + (hi << 2);
        float sv = 1.0f / (1.0f + __expf(-(acc[nt][r] + bgv)));
        outp[(m0 + crow) * 256 + nt * 32 + lo] = __float2bfloat16(sv);
      }
    }
  } else {
    #pragma unroll
    for (int nt = 0; nt < 8; ++nt) {
      #pragma unroll
      for (int r = 0; r < 16; ++r) {
        int crow = (r & 3) + ((r >> 2) << 3) + (hi << 2);
        outp[(m0 + crow) * 256 + nt * 32 + lo] = __float2bfloat16(acc[nt][r]);
      }
    }
  }
}

// ---------------------------------------------------------------------------
// Kernel 3b: vT[s][h][c][k] = vo[s][k][h*32+c]. One block per (s,h), LDS tile.
// ---------------------------------------------------------------------------
__global__ __launch_bounds__(256) void transpose_v_kernel(
    const bf16* __restrict__ vo, bf16* __restrict__ vT) {
  int s = blockIdx.x >> 3, h = blockIdx.x & 7;
  int t = threadIdx.x;
  __shared__ bf16 tile[256][40];  // stride 80 B (16B-aligned), conflict-light

  #pragma unroll
  for (int p = 0; p < 4; ++p) {
    int k = p * 64 + (t >> 2);
    int c0 = (t & 3) * 8;
    uint4 u = *(const uint4*)(vo + ((size_t)(s * 256 + k)) * 256 + h * 32 + c0);
    *(uint4*)&tile[k][c0] = u;
  }
  __syncthreads();

  int c = t >> 3, k0 = (t & 7) * 32;
  bf16 buf[32];
  #pragma unroll
  for (int j = 0; j < 32; ++j) buf[j] = tile[k0 + j][c];
  bf16* dst = vT + (((size_t)(s * 8 + h) * 32 + c) * 256 + k0);
  #pragma unroll
  for (int q = 0; q < 4; ++q)
    *(uint4*)(dst + q * 8) = *(const uint4*)(buf + q * 8);
}

// ---------------------------------------------------------------------------
// Kernel 4: MFMA attention, one wave per (s, h, 32-q tile). Two-half
// structure: k in [0,128) then [128,256), each half = QK MFMA burst (acc[4])
// -> bias+exp2 -> pack+PV; o accumulates across halves. Halved AGPR live
// range (acc[4] vs acc[8]) -> 3 waves/SIMD. Bias loads are float4 (32 per
// lane, wave-coalesced 1 KB). No-max softmax (log2-domain, bounded).
// XCD-swizzled block id for K/V L2 locality.
// ---------------------------------------------------------------------------
__global__ __launch_bounds__(256, 3) void attn_mfma_kernel(
    const bf16* __restrict__ qb, const bf16* __restrict__ kb,
    const bf16* __restrict__ vT, const bf16* __restrict__ gb,
    const float* __restrict__ biasP, bf16* __restrict__ gob) {
  // XCD swizzle: consecutive work ids (sharing s and (s,h) K/V slices)
  // land on one XCD's L2.
  int wb = (blockIdx.x & 7) * 512 + (blockIdx.x >> 3);
  int wid = wb * 4 + (threadIdx.x >> 6);
  int lane = threadIdx.x & 63;
  int lo = lane & 31;
  int hi = lane >> 5;
  int s = wid >> 6;
  int h = (wid >> 3) & 7;
  int qt = wid & 7;
  int q0 = qt * 32;

  const size_t base = (size_t)s * NR * 256 + h * CH;

  // this lane's 128 bias values as 32 float4s: bp4[i4*64], i4 = 0..31
  const float4* bp4 =
      (const float4*)biasP + ((size_t)(h * 8 + qt) * 32) * 64 + lane;

  short8 qf[2];
  #pragma unroll
  for (int cc = 0; cc < 2; ++cc)
    qf[cc] = load8(qb + base + (size_t)(q0 + lo) * 256 + cc * 16 + hi * 8);

  const bf16* vt = vT + ((size_t)(s * NH + h) * CH + lo) * 256;

  f32x16 o = {};
  float l0 = 0.0f, l1 = 0.0f, l2 = 0.0f, l3 = 0.0f;

  #pragma unroll
  for (int hs = 0; hs < 2; ++hs) {
    // --- QK^T burst for this half: acc[4] covers k in [hs*128, hs*128+128)
    f32x16 acc[4];
    __builtin_amdgcn_s_setprio(1);
    #pragma unroll
    for (int th = 0; th < 4; ++th) {
      int t = hs * 4 + th;
      short8 kf0 = load8(kb + base + (size_t)(t * 32 + lo) * 256 + hi * 8);
      short8 kf1 = load8(kb + base + (size_t)(t * 32 + lo) * 256 + 16 + hi * 8);
      f32x16 z = {};
      acc[th] = __builtin_amdgcn_mfma_f32_32x32x16_bf16(kf0, qf[0], z, 0, 0, 0);
      acc[th] =
          __builtin_amdgcn_mfma_f32_32x32x16_bf16(kf1, qf[1], acc[th], 0, 0, 0);
    }
    __builtin_amdgcn_s_setprio(0);

    // --- P = exp2(logit + bias), 4 parallel sum accumulators
    #pragma unroll
    for (int th = 0; th < 4; ++th) {
      int t = hs * 4 + th;
      #pragma unroll
      for (int j = 0; j < 4; ++j) {
        float4 b4 = bp4[(t * 4 + j) * 64];
        float e0 = exp2f(acc[th][j * 4 + 0] + b4.x);
        float e1 = exp2f(acc[th][j * 4 + 1] + b4.y);
        float e2 = exp2f(acc[th][j * 4 + 2] + b4.z);
        float e3 = exp2f(acc[th][j * 4 + 3] + b4.w);
        acc[th][j * 4 + 0] = e0;
        acc[th][j * 4 + 1] = e1;
        acc[th][j * 4 + 2] = e2;
        acc[th][j * 4 + 3] = e3;
        l0 += e0;
        l1 += e1;
        l2 += e2;
        l3 += e3;
      }
    }

    // --- pack P fragments + PV for this half's 8 16-k chunks
    #pragma unroll
    for (int kc2 = 0; kc2 < 8; ++kc2) {
      int th = kc2 >> 1;
      int rb = (kc2 & 1) << 3;
      unsigned uL0 = pk_bf16(acc[th][rb + 0], acc[th][rb + 1]);
      unsigned uL1 = pk_bf16(acc[th][rb + 2], acc[th][rb + 3]);
      unsigned uH0 = pk_bf16(acc[th][rb + 4], acc[th][rb + 5]);
      unsigned uH1 = pk_bf16(acc[th][rb + 6], acc[th][rb + 7]);
      unsigned sL0 = __shfl_xor(uL0, 32), sL1 = __shfl_xor(uL1, 32);
      unsigned sH0 = __shfl_xor(uH0, 32), sH1 = __shfl_xor(uH1, 32);
      uint4 pu;
      pu.x = hi ? sH0 : uL0;
      pu.y = hi ? sH1 : uL1;
      pu.z = hi ? uH0 : sL0;
      pu.w = hi ? uH1 : sL1;
      short8 pf = __builtin_bit_cast(short8, pu);
      short8 vf = load8(vt + (hs * 8 + kc2) * 16 + hi * 8);
      o = __builtin_amdgcn_mfma_f32_32x32x16_bf16(pf, vf, o, 0, 0, 0);
    }
  }

  float l = (l0 + l1) + (l2 + l3);
  l += __shfl_xor(l, 32);
  float linv = 1.0f / l;

  #pragma unroll
  for (int r = 0; r < 16; ++r) {
    int crow = (r & 3) + ((r >> 2) << 3) + (hi << 2);
    float li = __shfl(linv, crow);
    size_t idx = base + (size_t)(q0 + crow) * 256 + lo;
    float gg = __bfloat162float(gb[idx]);
    gob[idx] = __float2bfloat16(gg * o[r] * li);
  }
}

// ---------------------------------------------------------------------------
// Kernel 5: out = (g*o) @ w_o + b_o via MFMA, accumulator-resident form.
// ---------------------------------------------------------------------------
__global__ __launch_bounds__(256, 2) void out_mfma_kernel(
    const bf16* __restrict__ gob, const bf16* __restrict__ wop,
    const float* __restrict__ bo, float* __restrict__ out) {
  int wid = blockIdx.x * 4 + (threadIdx.x >> 6);
  int lane = threadIdx.x & 63;
  int lo = lane & 31, hi = lane >> 5;
  size_t m0 = (size_t)wid * 32;

  const bf16* arow = gob + (m0 + lo) * 256 + hi * 8;
  const bf16* wbase = wop + ((size_t)hi * 256 + lo) * 8;

  f32x16 acc[8] = {};
  #pragma unroll 2
  for (int kc = 0; kc < 16; ++kc) {
    short8 a = load8(arow + kc * 16);
    const bf16* wkc = wbase + (size_t)kc * 4096;
    #pragma unroll
    for (int nt = 0; nt < 8; ++nt) {
      short8 b = load8(wkc + nt * 256);
      acc[nt] = __builtin_amdgcn_mfma_f32_32x32x16_bf16(a, b, acc[nt], 0, 0, 0);
    }
  }

  #pragma unroll
  for (int nt = 0; nt < 8; ++nt) {
    float bv = bo[nt * 32 + lo];
    #pragma unroll
    for (int r = 0; r < 16; ++r) {
      int crow = (r & 3) + ((r >> 2) << 3) + (hi << 2);
      out[(m0 + crow) * 256 + nt * 32 + lo] = acc[nt][r] + bv;
    }
  }
}

// ---------------------------------------------------------------------------
extern "C" void kernel_launch(void* const* d_in, const int* in_sizes, int n_in,
                              void* d_out, int out_size, void* d_ws, size_t ws_size,
                              hipStream_t stream) {
  const float* m      = (const float*)d_in[0];
  const float* z      = (const float*)d_in[1];
  const float* ln_m_w = (const float*)d_in[2];
  const float* ln_m_b = (const float*)d_in[3];
  const float* ln_z_w = (const float*)d_in[4];
  const float* ln_z_b = (const float*)d_in[5];
  const float* w_z    = (const float*)d_in[6];
  const float* w_q    = (const float*)d_in[7];
  const float* w_k    = (const float*)d_in[8];
  const float* w_v    = (const float*)d_in[9];
  const float* w_g    = (const float*)d_in[10];
  const float* b_g    = (const float*)d_in[11];
  const float* w_o    = (const float*)d_in[12];
  const float* b_o    = (const float*)d_in[13];
  float* out = (float*)d_out;

  const size_t SZ = (size_t)NS * NR * 256;

  bf16* mn   = (bf16*)d_ws;
  bf16* qb   = mn + SZ;
  bf16* kb   = qb + SZ;
  bf16* vo   = kb + SZ;
  bf16* gb   = vo + SZ;
  bf16* gob  = gb + SZ;
  float* biasP = (float*)(gob + SZ);            // 2 MB
  bf16* wp   = (bf16*)(biasP + NH * NR * NR);   // 5*65536 bf16 = 640 KB
  bf16* wop  = wp + 4 * 65536;
  bf16* vT   = mn;  // mn is dead after qkvg; reuse its slot for vT

  pack_w_kernel<<<dim3(32, 5), 256, 0, stream>>>(w_q, w_k, w_v, w_g, w_o, wp);
  ln_m_kernel<<<(NS * NR) / 4, 256, 0, stream>>>(m, ln_m_w, ln_m_b, mn);
  bias_kernel<<<NR * NR, 128, 0, stream>>>(z, ln_z_w, ln_z_b, w_z, biasP);
  qkvg_mfma_kernel<<<(NS * NR) / 32, 256, 0, stream>>>(mn, wp, b_g,
                                                       qb, kb, vo, gb);
  transpose_v_kernel<<<NS * NH, 256, 0, stream>>>(vo, vT);
  attn_mfma_kernel<<<(NS * NH * 8) / 4, 256, 0, stream>>>(qb, kb, vT, gb,
                                                          biasP, gob);
  out_mfma_kernel<<<(NS * NR) / 32 / 4, 256, 0, stream>>>(gob, wop, b_o, out);
}